// Round 6
// baseline (1685.126 us; speedup 1.0000x reference)
//
#include <hip/hip_runtime.h>
#include <math.h>

// Problem constants
#define BG 1024
#define EPG 512
#define ETOT (BG*EPG)
#define DIM 512
#define KP1 52
#define KP2 42
#define KP3 34

typedef unsigned int uint;
typedef short s16x8 __attribute__((ext_vector_type(8)));
typedef float f32x4 __attribute__((ext_vector_type(4)));

// ---------------- bf16 split helpers ----------------
__device__ __forceinline__ unsigned short f2b(float x) {
    uint u = __float_as_uint(x);
    u = u + 0x7fffu + ((u >> 16) & 1u);
    return (unsigned short)(u >> 16);
}
__device__ __forceinline__ float b2f(unsigned short h) {
    return __uint_as_float(((uint)h) << 16);
}
__device__ __forceinline__ void splitf(float x, unsigned short& h, unsigned short& l) {
    h = f2b(x);
    l = f2b(x - b2f(h));
}
__device__ __forceinline__ uint pk2(unsigned short a, unsigned short b) {
    return (uint)a | ((uint)b << 16);
}

__device__ __forceinline__ void gload16(const void* g, void* l) {
    __builtin_amdgcn_global_load_lds(
        (const __attribute__((address_space(1))) void*)g,
        (__attribute__((address_space(3))) void*)l, 16, 0, 0);
}

// ---------------------------------------------------------------------------
// 1. Gather + split: X[i,:] = emb[ids[i],:]  ->  hi/lo bf16 planes
// ---------------------------------------------------------------------------
__global__ void __launch_bounds__(256)
gather_split(const int* __restrict__ ids, const float* __restrict__ emb,
             unsigned short* __restrict__ Xhi, unsigned short* __restrict__ Xlo)
{
    int tid = blockIdx.x * 256 + threadIdx.x;    // rows*64, 8 elems each
    int row = tid >> 6;
    int c8  = (tid & 63) * 8;
    const float4* s = (const float4*)(emb + (size_t)ids[row] * DIM + c8);
    float4 v0 = s[0], v1 = s[1];
    float vs[8] = {v0.x,v0.y,v0.z,v0.w,v1.x,v1.y,v1.z,v1.w};
    unsigned short h[8], l[8];
#pragma unroll
    for (int i = 0; i < 8; ++i) splitf(vs[i], h[i], l[i]);
    uint4 H, L;
    H.x = pk2(h[0],h[1]); H.y = pk2(h[2],h[3]); H.z = pk2(h[4],h[5]); H.w = pk2(h[6],h[7]);
    L.x = pk2(l[0],l[1]); L.y = pk2(l[2],l[3]); L.z = pk2(l[4],l[5]); L.w = pk2(l[6],l[7]);
    *(uint4*)(Xhi + (size_t)row * DIM + c8) = H;
    *(uint4*)(Xlo + (size_t)row * DIM + c8) = L;
}

// ---------------------------------------------------------------------------
// 2. Weight convert, all 6 weights in one launch
// ---------------------------------------------------------------------------
struct WPtrs { const float* w[6]; };

__global__ void __launch_bounds__(256)
split_wT_all(WPtrs p, unsigned short* __restrict__ WT)
{
    const int wi = blockIdx.x >> 8;
    const int bb = blockIdx.x & 255;
    const float* W = p.w[wi];
    unsigned short* Thi = WT + (size_t)(2 * wi) * DIM * DIM;
    unsigned short* Tlo = Thi + (size_t)DIM * DIM;
    __shared__ float tl[32][33];
    const int t  = threadIdx.x;
    const int bx = bb & 15;   // n-tile
    const int by = bb >> 4;   // k-tile
    const int lx = t & 31, ly = t >> 5;
    for (int r = ly; r < 32; r += 8)
        tl[r][lx] = W[(size_t)(by*32 + r) * DIM + bx*32 + lx];
    __syncthreads();
    for (int r = ly; r < 32; r += 8) {
        float v = tl[lx][r];
        unsigned short h, l; splitf(v, h, l);
        size_t o = (size_t)(bx*32 + r) * DIM + by*32 + lx;
        Thi[o] = h; Tlo[o] = l;
    }
}

// ---------------------------------------------------------------------------
// 3. Mean aggregation, column-sliced (unchanged from round 5)
// ---------------------------------------------------------------------------
template<int NPER>
__global__ void __launch_bounds__(256, 4)
agg_lds4(const unsigned short* __restrict__ Xhi, const unsigned short* __restrict__ Xlo,
         const int* __restrict__ esrc, const int* __restrict__ edst,
         const float* __restrict__ emask,
         unsigned short* __restrict__ Ghi, unsigned short* __restrict__ Glo)
{
    const int g  = blockIdx.x >> 2;
    const int c0 = (blockIdx.x & 3) * 128;
    const int t  = threadIdx.x;
    __shared__ __align__(16) unsigned short xs[NPER * 256];
    __shared__ int ldst[EPG];
    __shared__ int lsrc[EPG];
    __shared__ int ssrc[EPG];
    __shared__ int cnt4[4][64];
    __shared__ int offs[NPER + 1];

    for (int s = t; s < NPER * 32; s += 256) {
        const int row  = s >> 5;
        const int half = (s >> 4) & 1;
        const int c8   = (s & 15) * 8;
        const unsigned short* src =
            (half ? Xlo : Xhi) + (size_t)(g * NPER + row) * DIM + c0 + c8;
        gload16(src, (char*)xs + (size_t)s * 16);
    }
    const int eb = g * EPG;
    for (int e = t; e < EPG; e += 256) {
        float m = emask ? emask[eb + e] : 1.0f;
        ldst[e] = (m > 0.f) ? (edst[eb + e] - g * NPER) : -1;
        lsrc[e] = esrc[eb + e] - g * NPER;
    }
    __syncthreads();
    {
        const int d = t & 63, q = t >> 6;
        int c = 0;
        for (int e = q * 128; e < q * 128 + 128; ++e) c += (ldst[e] == d);
        cnt4[q][d] = c;
    }
    __syncthreads();
    if (t == 0) {
        int s = 0;
        for (int i = 0; i < NPER; ++i) {
            offs[i] = s;
            s += cnt4[0][i] + cnt4[1][i] + cnt4[2][i] + cnt4[3][i];
        }
        offs[NPER] = s;
    }
    __syncthreads();
    {
        const int d = t & 63, q = t >> 6;
        if (d < NPER) {
            int w = offs[d];
            for (int q2 = 0; q2 < q; ++q2) w += cnt4[q2][d];
            for (int e = q * 128; e < q * 128 + 128; ++e)
                if (ldst[e] == d) ssrc[w++] = lsrc[e];
        }
    }
    __syncthreads();
    const int ch = (t & 31) * 4;
    const int d0 = t >> 5;
    for (int d = d0; d < NPER; d += 8) {
        const int cA = offs[d], cB = offs[d + 1];
        float s0 = 0.f, s1 = 0.f, s2 = 0.f, s3 = 0.f;
        for (int j = cA; j < cB; ++j) {
            const int base = ssrc[j] * 256 + ch;
            ushort4 h = *(const ushort4*)&xs[base];
            ushort4 l = *(const ushort4*)&xs[base + 128];
            s0 += b2f(h.x) + b2f(l.x);
            s1 += b2f(h.y) + b2f(l.y);
            s2 += b2f(h.z) + b2f(l.z);
            s3 += b2f(h.w) + b2f(l.w);
        }
        const float den = fmaxf((float)(cB - cA), 1.0f);
        s0 /= den; s1 /= den; s2 /= den; s3 /= den;
        unsigned short h0,h1,h2,h3,l0,l1,l2,l3;
        splitf(s0,h0,l0); splitf(s1,h1,l1); splitf(s2,h2,l2); splitf(s3,h3,l3);
        const size_t wo = (size_t)(g * NPER + d) * DIM + c0 + ch;
        *(uint2*)(Ghi + wo) = make_uint2(pk2(h0,h1), pk2(h2,h3));
        *(uint2*)(Glo + wo) = make_uint2(pk2(l0,l1), pk2(l2,l3));
    }
}

// ---------------------------------------------------------------------------
// 4. Split-bf16 MFMA GEMM, 256x256 tile, BK=64, 8 waves, phase-interleaved
//    (T2 swizzle + T3 phases + T5 setprio; depth-1 prefetch, vmcnt(0) at
//     tile top only). 48 flat K-tiles = 6 plane-segments x 8.
// ---------------------------------------------------------------------------
__global__ void __launch_bounds__(512)
gemm_sage8(const unsigned short* __restrict__ Ghi, const unsigned short* __restrict__ Glo,
           const unsigned short* __restrict__ WLhi, const unsigned short* __restrict__ WLlo,
           const unsigned short* __restrict__ Xhi, const unsigned short* __restrict__ Xlo,
           const unsigned short* __restrict__ WRhi, const unsigned short* __restrict__ WRlo,
           const float* __restrict__ bias, float* __restrict__ C, int M)
{
    __shared__ unsigned short sA[2][256 * 64];   // 32 KB each
    __shared__ unsigned short sW[2][256 * 64];   // total 128 KB

    const int t = threadIdx.x;                   // 0..511
    const uint nwg = gridDim.x;                  // multiple of 8
    const uint q8  = nwg >> 3;
    const uint bid = blockIdx.x;
    const uint sw  = (bid & 7) * q8 + (bid >> 3);
    const int  m0  = (int)(sw >> 1) * 256;
    const int  n0  = (int)(sw & 1) * 256;

    const int l  = t & 63;
    const int w  = t >> 6;       // 0..7
    const int wr = w >> 2;       // 0..1 : row half (128 rows)
    const int wc = w & 3;        // 0..3 : col quarter (64 cols)
    const int lr = l & 15;
    const int lq = l >> 4;       // 0..3

    f32x4 acc[8][4];
#pragma unroll
    for (int i = 0; i < 8; ++i)
#pragma unroll
        for (int j = 0; j < 4; ++j) acc[i][j] = (f32x4){0.f, 0.f, 0.f, 0.f};

    // staging geometry: 4 slots/thread/matrix; phys chunk pc holds logical
    // chunk pc^(row&7)  (same involution as the ds_read side)
    uint srow[4], soff[4];
#pragma unroll
    for (int i = 0; i < 4; ++i) {
        uint p = (uint)i * 512u + (uint)t;
        srow[i] = p >> 3;
        soff[i] = ((p & 7u) ^ (srow[i] & 7u)) * 8u;
    }

    // segment lookup (uniform)
    const unsigned short* Aseg;
    const unsigned short* Wseg;
    int kb;
#define SEGSEL(kt)                                                     \
    {   int s_ = (kt) >> 3; kb = ((kt) & 7) << 6;                      \
        if      (s_ == 0) { Aseg = Ghi; Wseg = WLhi; }                 \
        else if (s_ == 1) { Aseg = Ghi; Wseg = WLlo; }                 \
        else if (s_ == 2) { Aseg = Glo; Wseg = WLhi; }                 \
        else if (s_ == 3) { Aseg = Xhi; Wseg = WRhi; }                 \
        else if (s_ == 4) { Aseg = Xhi; Wseg = WRlo; }                 \
        else              { Aseg = Xlo; Wseg = WRhi; } }

#define STAGE(dst)                                                     \
    _Pragma("unroll")                                                  \
    for (int i = 0; i < 4; ++i) {                                      \
        const unsigned short* ga =                                     \
            Aseg + (size_t)(m0 + (int)srow[i]) * DIM + kb + soff[i];   \
        const unsigned short* gw =                                     \
            Wseg + (size_t)(n0 + (int)srow[i]) * DIM + kb + soff[i];   \
        uint p16 = ((uint)i * 512u + (uint)t) * 16u;                   \
        gload16(ga, (char*)sA[dst] + p16);                             \
        gload16(gw, (char*)sW[dst] + p16);                             \
    }

    // prologue: stage tile 0
    SEGSEL(0);
    STAGE(0);
    int cur = 0;

#pragma unroll 1
    for (int kt = 0; kt < 48; ++kt) {
        asm volatile("s_waitcnt vmcnt(0)" ::: "memory");
        __syncthreads();                          // buf[cur] ready for all
        if (kt < 47) {
            SEGSEL(kt + 1);
            STAGE(cur ^ 1);                       // prefetch flies over phases
        }
        __builtin_amdgcn_sched_barrier(0);
        const char* la = (const char*)sA[cur];
        const char* lw = (const char*)sW[cur];
#pragma unroll
        for (int p = 0; p < 4; ++p) {
            const int ks = p >> 1;                // K=32 slice
            const int mh = p & 1;                 // m-frag half
            s16x8 af[4], wf[4];
#pragma unroll
            for (int i2 = 0; i2 < 4; ++i2) {
                int arow = wr * 128 + (mh * 4 + i2) * 16 + lr;
                int off  = arow * 128 + 16 * ((ks * 4 + lq) ^ (arow & 7));
                af[i2] = *(const s16x8*)(la + off);
            }
#pragma unroll
            for (int j = 0; j < 4; ++j) {
                int wrow = wc * 64 + j * 16 + lr;
                int off  = wrow * 128 + 16 * ((ks * 4 + lq) ^ (wrow & 7));
                wf[j] = *(const s16x8*)(lw + off);
            }
            __builtin_amdgcn_sched_barrier(0);
            __syncthreads();
            __builtin_amdgcn_s_setprio(1);
#pragma unroll
            for (int i2 = 0; i2 < 4; ++i2)
#pragma unroll
                for (int j = 0; j < 4; ++j)
                    acc[mh * 4 + i2][j] = __builtin_amdgcn_mfma_f32_16x16x32_bf16(
                        af[i2], wf[j], acc[mh * 4 + i2][j], 0, 0, 0);
            __builtin_amdgcn_s_setprio(0);
            __builtin_amdgcn_sched_barrier(0);
            __syncthreads();
        }
        cur ^= 1;
    }
#undef STAGE
#undef SEGSEL

    // epilogue: bias + relu, fp32 out
#pragma unroll
    for (int i = 0; i < 8; ++i) {
        const int r0 = m0 + wr * 128 + i * 16 + lq * 4;
#pragma unroll
        for (int j = 0; j < 4; ++j) {
            const int cc = n0 + wc * 64 + j * 16 + lr;
            const float bv = bias[cc];
#pragma unroll
            for (int r = 0; r < 4; ++r) {
                float v = acc[i][j][r] + bv;
                C[(size_t)(r0 + r) * DIM + cc] = fmaxf(v, 0.f);
            }
        }
    }
}

// ---------------------------------------------------------------------------
// 5. TopK pooling: rank in fp32, gate, write split planes
// ---------------------------------------------------------------------------
template<int NPER, int KEEP>
__global__ void __launch_bounds__(256)
topk_split(const float* __restrict__ Y, const float* __restrict__ p,
           unsigned short* __restrict__ Xhi, unsigned short* __restrict__ Xlo,
           int* __restrict__ newid)
{
    const int g = blockIdx.x;
    const int t = threadIdx.x;
    const int wave = t >> 6, lane = t & 63;
    __shared__ float ssc[NPER];
    __shared__ float spnorm;
    __shared__ int   perm[KEEP];
    __shared__ float sgate[KEEP];

    if (wave == 0) {
        float v = 0.f;
#pragma unroll
        for (int i = 0; i < 8; ++i) { float x = p[lane + i * 64]; v = fmaf(x, x, v); }
#pragma unroll
        for (int off = 32; off; off >>= 1) v += __shfl_down(v, off);
        if (lane == 0) spnorm = sqrtf(v);
    }
    for (int nl = wave; nl < NPER; nl += 4) {
        const float* yr = Y + (size_t)(g * NPER + nl) * DIM;
        float v = 0.f;
#pragma unroll
        for (int i = 0; i < 8; ++i) v = fmaf(yr[lane + i * 64], p[lane + i * 64], v);
#pragma unroll
        for (int off = 32; off; off >>= 1) v += __shfl_down(v, off);
        if (lane == 0) ssc[nl] = v;
    }
    __syncthreads();
    float s = 0.f;
    if (t < NPER) s = tanhf(ssc[t] / spnorm);
    __syncthreads();
    if (t < NPER) ssc[t] = s;
    __syncthreads();
    if (t < NPER) {
        int r = 0;
        for (int j = 0; j < NPER; ++j) {
            float sj = ssc[j];
            r += (sj > s) || (sj == s && j < t);
        }
        newid[g * NPER + t] = (r < KEEP) ? (g * KEEP + r) : -1;
        if (r < KEEP) { perm[r] = t; sgate[r] = s; }
    }
    __syncthreads();
    for (int r = 0; r < KEEP; ++r) {
        const float2* src = (const float2*)(Y + (size_t)(g * NPER + perm[r]) * DIM);
        const float sv = sgate[r];
        float2 v = src[t];
        float a = v.x * sv, b = v.y * sv;
        unsigned short ha, la, hb, lb;
        splitf(a, ha, la); splitf(b, hb, lb);
        size_t o = (size_t)(g * KEEP + r) * DIM + 2 * t;
        *(uint*)(Xhi + o) = pk2(ha, hb);
        *(uint*)(Xlo + o) = pk2(la, lb);
    }
}

// ---------------------------------------------------------------------------
// 6. Edge remap after pooling
// ---------------------------------------------------------------------------
__global__ void __launch_bounds__(256)
remap_kernel(const int* __restrict__ es, const int* __restrict__ ed,
             const float* __restrict__ em, const int* __restrict__ newid,
             int* __restrict__ nes, int* __restrict__ ned, float* __restrict__ nem)
{
    int e = blockIdx.x * 256 + threadIdx.x;
    if (e >= ETOT) return;
    float m = em ? em[e] : 1.f;
    int s = newid[es[e]];
    int d = newid[ed[e]];
    bool v = (m > 0.f) && (s >= 0) && (d >= 0);
    nes[e] = v ? s : 0;
    ned[e] = v ? d : 0;
    nem[e] = v ? 1.f : 0.f;
}

// ---------------------------------------------------------------------------
// 7. Readout from split planes
// ---------------------------------------------------------------------------
__global__ void __launch_bounds__(256)
readout_split(const unsigned short* __restrict__ Xhi, const unsigned short* __restrict__ Xlo,
              float* __restrict__ H, int keep, int init)
{
    const int g = blockIdx.x;
    const int t = threadIdx.x;
    for (int c = t; c < DIM; c += 256) {
        float mx = -1e30f, sm = 0.f;
        for (int r = 0; r < keep; ++r) {
            size_t o = (size_t)(g * keep + r) * DIM + c;
            float v = b2f(Xhi[o]) + b2f(Xlo[o]);
            mx = fmaxf(mx, v); sm += v;
        }
        float mean = sm / (float)keep;
        size_t o = (size_t)g * 1024;
        if (init) { H[o + c] = mx;  H[o + 512 + c] = mean; }
        else      { H[o + c] += mx; H[o + 512 + c] += mean; }
    }
}

// ---------------------------------------------------------------------------
// 8. Fused MLP head
// ---------------------------------------------------------------------------
__global__ void __launch_bounds__(256)
mlp_fused(const float* __restrict__ H,
          const float* __restrict__ lw1, const float* __restrict__ lb1,
          const float* __restrict__ lw2, const float* __restrict__ lb2,
          const float* __restrict__ lw3, const float* __restrict__ lb3,
          const float* __restrict__ lw4, const float* __restrict__ lb4,
          const float* __restrict__ lw5, const float* __restrict__ lb5,
          float* __restrict__ out)
{
    __shared__ float h0[2][1024];
    __shared__ float y1[2][512];
    __shared__ float y2[2][256];
    __shared__ float y3[2][128];
    __shared__ float y4[2][64];
    const int t = threadIdx.x;
    const int r0 = blockIdx.x * 2;

    {
        float4 a = *(const float4*)&H[(size_t)r0 * 1024 + t * 4];
        float4 b = *(const float4*)&H[(size_t)(r0 + 1) * 1024 + t * 4];
        *(float4*)&h0[0][t * 4] = a;
        *(float4*)&h0[1][t * 4] = b;
    }
    __syncthreads();
    {
        float a00 = 0.f, a01 = 0.f, a10 = 0.f, a11 = 0.f;
        const int c = t * 2;
#pragma unroll 4
        for (int k = 0; k < 1024; ++k) {
            float2 wv = *(const float2*)&lw1[(size_t)k * 512 + c];
            float x0 = h0[0][k], x1 = h0[1][k];
            a00 = fmaf(x0, wv.x, a00); a01 = fmaf(x0, wv.y, a01);
            a10 = fmaf(x1, wv.x, a10); a11 = fmaf(x1, wv.y, a11);
        }
        y1[0][c]     = fmaxf(a00 + lb1[c], 0.f);
        y1[0][c + 1] = fmaxf(a01 + lb1[c + 1], 0.f);
        y1[1][c]     = fmaxf(a10 + lb1[c], 0.f);
        y1[1][c + 1] = fmaxf(a11 + lb1[c + 1], 0.f);
    }
    __syncthreads();
    {
        float a0 = 0.f, a1 = 0.f;
#pragma unroll 4
        for (int k = 0; k < 512; ++k) {
            float wv = lw2[(size_t)k * 256 + t];
            a0 = fmaf(y1[0][k], wv, a0);
            a1 = fmaf(y1[1][k], wv, a1);
        }
        y2[0][t] = fmaxf(a0 + lb2[t], 0.f);
        y2[1][t] = fmaxf(a1 + lb2[t], 0.f);
    }
    __syncthreads();
    if (t < 128) {
        float a0 = 0.f, a1 = 0.f;
#pragma unroll 4
        for (int k = 0; k < 256; ++k) {
            float wv = lw3[(size_t)k * 128 + t];
            a0 = fmaf(y2[0][k], wv, a0);
            a1 = fmaf(y2[1][k], wv, a1);
        }
        y3[0][t] = fmaxf(a0 + lb3[t], 0.f);
        y3[1][t] = fmaxf(a1 + lb3[t], 0.f);
    }
    __syncthreads();
    if (t < 64) {
        float a0 = 0.f, a1 = 0.f;
#pragma unroll 4
        for (int k = 0; k < 128; ++k) {
            float wv = lw4[(size_t)k * 64 + t];
            a0 = fmaf(y3[0][k], wv, a0);
            a1 = fmaf(y3[1][k], wv, a1);
        }
        y4[0][t] = fmaxf(a0 + lb4[t], 0.f);
        y4[1][t] = fmaxf(a1 + lb4[t], 0.f);
    }
    __syncthreads();
    const int wv = t >> 6, ln = t & 63;
    if (wv < 2) {
        float v = y4[wv][ln] * lw5[ln];
#pragma unroll
        for (int off = 32; off; off >>= 1) v += __shfl_down(v, off);
        if (ln == 0) out[r0 + wv] = 1.f / (1.f + expf(-(v + lb5[0])));
    }
}

// ---------------------------------------------------------------------------
extern "C" void kernel_launch(void* const* d_in, const int* in_sizes, int n_in,
                              void* d_out, int out_size, void* d_ws, size_t ws_size,
                              hipStream_t stream)
{
    const int*   x_ids = (const int*)d_in[0];
    const int*   esrc  = (const int*)d_in[1];
    const int*   edst  = (const int*)d_in[2];
    const float* emb   = (const float*)d_in[3];
    const float* w1l = (const float*)d_in[4],  *b1l = (const float*)d_in[5],  *w1r = (const float*)d_in[6];
    const float* w2l = (const float*)d_in[7],  *b2l = (const float*)d_in[8],  *w2r = (const float*)d_in[9];
    const float* w3l = (const float*)d_in[10], *b3l = (const float*)d_in[11], *w3r = (const float*)d_in[12];
    const float* p1  = (const float*)d_in[13];
    const float* p2  = (const float*)d_in[14];
    const float* p3  = (const float*)d_in[15];
    const float* lw1 = (const float*)d_in[16], *lb1 = (const float*)d_in[17];
    const float* lw2 = (const float*)d_in[18], *lb2 = (const float*)d_in[19];
    const float* lw3 = (const float*)d_in[20], *lb3 = (const float*)d_in[21];
    const float* lw4 = (const float*)d_in[22], *lb4 = (const float*)d_in[23];
    const float* lw5 = (const float*)d_in[24], *lb5 = (const float*)d_in[25];
    float* out = (float*)d_out;

    // ---- workspace layout ----
    const size_t PL = (size_t)65536 * DIM;
    unsigned short* Xhi = (unsigned short*)d_ws;
    unsigned short* Xlo = Xhi + PL;
    unsigned short* Ghi = Xlo + PL;
    unsigned short* Glo = Ghi + PL;
    float* Cc = (float*)(Glo + PL);
    float* H  = Cc + PL;
    int* newid = (int*)(H + (size_t)1024 * 1024);
    int*   ES2 = newid + 65536;
    int*   ED2 = ES2 + ETOT;
    float* EM2 = (float*)(ED2 + ETOT);
    int*   ES3 = (int*)(EM2 + ETOT);
    int*   ED3 = ES3 + ETOT;
    float* EM3 = (float*)(ED3 + ETOT);
    unsigned short* WT = (unsigned short*)(EM3 + ETOT);  // 12 planes x 512*512
    const size_t WSZ = (size_t)DIM * DIM;
    unsigned short *w1lh = WT + 0*WSZ,  *w1ll = WT + 1*WSZ;
    unsigned short *w1rh = WT + 2*WSZ,  *w1rl = WT + 3*WSZ;
    unsigned short *w2lh = WT + 4*WSZ,  *w2ll = WT + 5*WSZ;
    unsigned short *w2rh = WT + 6*WSZ,  *w2rl = WT + 7*WSZ;
    unsigned short *w3lh = WT + 8*WSZ,  *w3ll = WT + 9*WSZ;
    unsigned short *w3rh = WT + 10*WSZ, *w3rl = WT + 11*WSZ;

    // ---- weight conversion (one launch) ----
    WPtrs wp;
    wp.w[0] = w1l; wp.w[1] = w1r; wp.w[2] = w2l;
    wp.w[3] = w2r; wp.w[4] = w3l; wp.w[5] = w3r;
    split_wT_all<<<6 * 256, 256, 0, stream>>>(wp, WT);

    // ---- layer 1 ----
    gather_split<<<16384, 256, 0, stream>>>(x_ids, emb, Xhi, Xlo);
    agg_lds4<64><<<BG * 4, 256, 0, stream>>>(Xhi, Xlo, esrc, edst, nullptr, Ghi, Glo);
    gemm_sage8<<<(65536/256)*2, 512, 0, stream>>>(Ghi, Glo, w1lh, w1ll,
                                                  Xhi, Xlo, w1rh, w1rl, b1l, Cc, 65536);
    topk_split<64, KP1><<<BG, 256, 0, stream>>>(Cc, p1, Xhi, Xlo, newid);
    remap_kernel<<<ETOT/256, 256, 0, stream>>>(esrc, edst, nullptr, newid, ES2, ED2, EM2);
    readout_split<<<BG, 256, 0, stream>>>(Xhi, Xlo, H, KP1, 1);

    // ---- layer 2 ----
    agg_lds4<KP1><<<BG * 4, 256, 0, stream>>>(Xhi, Xlo, ES2, ED2, EM2, Ghi, Glo);
    gemm_sage8<<<(53248/256)*2, 512, 0, stream>>>(Ghi, Glo, w2lh, w2ll,
                                                  Xhi, Xlo, w2rh, w2rl, b2l, Cc, 53248);
    topk_split<KP1, KP2><<<BG, 256, 0, stream>>>(Cc, p2, Xhi, Xlo, newid);
    remap_kernel<<<ETOT/256, 256, 0, stream>>>(ES2, ED2, EM2, newid, ES3, ED3, EM3);
    readout_split<<<BG, 256, 0, stream>>>(Xhi, Xlo, H, KP2, 0);

    // ---- layer 3 ----
    agg_lds4<KP2><<<BG * 4, 256, 0, stream>>>(Xhi, Xlo, ES3, ED3, EM3, Ghi, Glo);
    gemm_sage8<<<(43008/256)*2, 512, 0, stream>>>(Ghi, Glo, w3lh, w3ll,
                                                  Xhi, Xlo, w3rh, w3rl, b3l, Cc, 43008);
    topk_split<KP2, KP3><<<BG, 256, 0, stream>>>(Cc, p3, Xhi, Xlo, newid);
    readout_split<<<BG, 256, 0, stream>>>(Xhi, Xlo, H, KP3, 0);

    // ---- fused MLP head ----
    mlp_fused<<<512, 256, 0, stream>>>(H, lw1, lb1, lw2, lb2, lw3, lb3,
                                       lw4, lb4, lw5, lb5, out);
}

// Round 7
// 1305.611 us; speedup vs baseline: 1.2907x; 1.2907x over previous
//
#include <hip/hip_runtime.h>
#include <math.h>

// Problem constants
#define BG 1024
#define EPG 512
#define ETOT (BG*EPG)
#define DIM 512
#define KP1 52
#define KP2 42
#define KP3 34

typedef unsigned int uint;
typedef short s16x8 __attribute__((ext_vector_type(8)));
typedef float f32x4 __attribute__((ext_vector_type(4)));

// ---------------- bf16 split helpers ----------------
__device__ __forceinline__ unsigned short f2b(float x) {
    uint u = __float_as_uint(x);
    u = u + 0x7fffu + ((u >> 16) & 1u);
    return (unsigned short)(u >> 16);
}
__device__ __forceinline__ float b2f(unsigned short h) {
    return __uint_as_float(((uint)h) << 16);
}
__device__ __forceinline__ void splitf(float x, unsigned short& h, unsigned short& l) {
    h = f2b(x);
    l = f2b(x - b2f(h));
}
__device__ __forceinline__ uint pk2(unsigned short a, unsigned short b) {
    return (uint)a | ((uint)b << 16);
}

__device__ __forceinline__ void gload16(const void* g, void* l) {
    __builtin_amdgcn_global_load_lds(
        (const __attribute__((address_space(1))) void*)g,
        (__attribute__((address_space(3))) void*)l, 16, 0, 0);
}

// ---------------------------------------------------------------------------
// 1. Gather + split: X[i,:] = emb[ids[i],:]  ->  hi/lo bf16 planes
// ---------------------------------------------------------------------------
__global__ void __launch_bounds__(256)
gather_split(const int* __restrict__ ids, const float* __restrict__ emb,
             unsigned short* __restrict__ Xhi, unsigned short* __restrict__ Xlo)
{
    int tid = blockIdx.x * 256 + threadIdx.x;    // rows*64, 8 elems each
    int row = tid >> 6;
    int c8  = (tid & 63) * 8;
    const float4* s = (const float4*)(emb + (size_t)ids[row] * DIM + c8);
    float4 v0 = s[0], v1 = s[1];
    float vs[8] = {v0.x,v0.y,v0.z,v0.w,v1.x,v1.y,v1.z,v1.w};
    unsigned short h[8], l[8];
#pragma unroll
    for (int i = 0; i < 8; ++i) splitf(vs[i], h[i], l[i]);
    uint4 H, L;
    H.x = pk2(h[0],h[1]); H.y = pk2(h[2],h[3]); H.z = pk2(h[4],h[5]); H.w = pk2(h[6],h[7]);
    L.x = pk2(l[0],l[1]); L.y = pk2(l[2],l[3]); L.z = pk2(l[4],l[5]); L.w = pk2(l[6],l[7]);
    *(uint4*)(Xhi + (size_t)row * DIM + c8) = H;
    *(uint4*)(Xlo + (size_t)row * DIM + c8) = L;
}

// ---------------------------------------------------------------------------
// 2. Weight convert, all 6 weights in one launch
// ---------------------------------------------------------------------------
struct WPtrs { const float* w[6]; };

__global__ void __launch_bounds__(256)
split_wT_all(WPtrs p, unsigned short* __restrict__ WT)
{
    const int wi = blockIdx.x >> 8;
    const int bb = blockIdx.x & 255;
    const float* W = p.w[wi];
    unsigned short* Thi = WT + (size_t)(2 * wi) * DIM * DIM;
    unsigned short* Tlo = Thi + (size_t)DIM * DIM;
    __shared__ float tl[32][33];
    const int t  = threadIdx.x;
    const int bx = bb & 15;   // n-tile
    const int by = bb >> 4;   // k-tile
    const int lx = t & 31, ly = t >> 5;
    for (int r = ly; r < 32; r += 8)
        tl[r][lx] = W[(size_t)(by*32 + r) * DIM + bx*32 + lx];
    __syncthreads();
    for (int r = ly; r < 32; r += 8) {
        float v = tl[lx][r];
        unsigned short h, l; splitf(v, h, l);
        size_t o = (size_t)(bx*32 + r) * DIM + by*32 + lx;
        Thi[o] = h; Tlo[o] = l;
    }
}

// ---------------------------------------------------------------------------
// 3. Mean aggregation, column-sliced (unchanged from round 5)
// ---------------------------------------------------------------------------
template<int NPER>
__global__ void __launch_bounds__(256, 4)
agg_lds4(const unsigned short* __restrict__ Xhi, const unsigned short* __restrict__ Xlo,
         const int* __restrict__ esrc, const int* __restrict__ edst,
         const float* __restrict__ emask,
         unsigned short* __restrict__ Ghi, unsigned short* __restrict__ Glo)
{
    const int g  = blockIdx.x >> 2;
    const int c0 = (blockIdx.x & 3) * 128;
    const int t  = threadIdx.x;
    __shared__ __align__(16) unsigned short xs[NPER * 256];
    __shared__ int ldst[EPG];
    __shared__ int lsrc[EPG];
    __shared__ int ssrc[EPG];
    __shared__ int cnt4[4][64];
    __shared__ int offs[NPER + 1];

    for (int s = t; s < NPER * 32; s += 256) {
        const int row  = s >> 5;
        const int half = (s >> 4) & 1;
        const int c8   = (s & 15) * 8;
        const unsigned short* src =
            (half ? Xlo : Xhi) + (size_t)(g * NPER + row) * DIM + c0 + c8;
        gload16(src, (char*)xs + (size_t)s * 16);
    }
    const int eb = g * EPG;
    for (int e = t; e < EPG; e += 256) {
        float m = emask ? emask[eb + e] : 1.0f;
        ldst[e] = (m > 0.f) ? (edst[eb + e] - g * NPER) : -1;
        lsrc[e] = esrc[eb + e] - g * NPER;
    }
    __syncthreads();
    {
        const int d = t & 63, q = t >> 6;
        int c = 0;
        for (int e = q * 128; e < q * 128 + 128; ++e) c += (ldst[e] == d);
        cnt4[q][d] = c;
    }
    __syncthreads();
    if (t == 0) {
        int s = 0;
        for (int i = 0; i < NPER; ++i) {
            offs[i] = s;
            s += cnt4[0][i] + cnt4[1][i] + cnt4[2][i] + cnt4[3][i];
        }
        offs[NPER] = s;
    }
    __syncthreads();
    {
        const int d = t & 63, q = t >> 6;
        if (d < NPER) {
            int w = offs[d];
            for (int q2 = 0; q2 < q; ++q2) w += cnt4[q2][d];
            for (int e = q * 128; e < q * 128 + 128; ++e)
                if (ldst[e] == d) ssrc[w++] = lsrc[e];
        }
    }
    __syncthreads();
    const int ch = (t & 31) * 4;
    const int d0 = t >> 5;
    for (int d = d0; d < NPER; d += 8) {
        const int cA = offs[d], cB = offs[d + 1];
        float s0 = 0.f, s1 = 0.f, s2 = 0.f, s3 = 0.f;
        for (int j = cA; j < cB; ++j) {
            const int base = ssrc[j] * 256 + ch;
            ushort4 h = *(const ushort4*)&xs[base];
            ushort4 l = *(const ushort4*)&xs[base + 128];
            s0 += b2f(h.x) + b2f(l.x);
            s1 += b2f(h.y) + b2f(l.y);
            s2 += b2f(h.z) + b2f(l.z);
            s3 += b2f(h.w) + b2f(l.w);
        }
        const float den = fmaxf((float)(cB - cA), 1.0f);
        s0 /= den; s1 /= den; s2 /= den; s3 /= den;
        unsigned short h0,h1,h2,h3,l0,l1,l2,l3;
        splitf(s0,h0,l0); splitf(s1,h1,l1); splitf(s2,h2,l2); splitf(s3,h3,l3);
        const size_t wo = (size_t)(g * NPER + d) * DIM + c0 + ch;
        *(uint2*)(Ghi + wo) = make_uint2(pk2(h0,h1), pk2(h2,h3));
        *(uint2*)(Glo + wo) = make_uint2(pk2(l0,l1), pk2(l2,l3));
    }
}

// ---------------------------------------------------------------------------
// 4. Split-bf16 MFMA GEMM (round-5 version, proven ~900 TF)
// ---------------------------------------------------------------------------
__global__ void __launch_bounds__(256)
gemm_sage(const unsigned short* __restrict__ Ghi, const unsigned short* __restrict__ Glo,
          const unsigned short* __restrict__ WLhi, const unsigned short* __restrict__ WLlo,
          const unsigned short* __restrict__ Xhi, const unsigned short* __restrict__ Xlo,
          const unsigned short* __restrict__ WRhi, const unsigned short* __restrict__ WRlo,
          const float* __restrict__ bias, float* __restrict__ C, int M)
{
    __shared__ unsigned short sA[128 * 64];
    __shared__ unsigned short sW[128 * 64];

    const int t = threadIdx.x;
    const uint nwg = gridDim.x;
    const uint q8  = nwg >> 3;
    const uint bid = blockIdx.x;
    const uint sw  = (bid & 7) * q8 + (bid >> 3);
    const int  m0  = (int)(sw >> 2) * 128;
    const int  n0  = (int)(sw & 3) * 128;

    const int l  = t & 63;
    const int w  = t >> 6;
    const int wr = w >> 1;
    const int wc = w & 1;
    const int lr = l & 15;
    const int lq = l >> 4;

    f32x4 acc[4][4];
#pragma unroll
    for (int i = 0; i < 4; ++i)
#pragma unroll
        for (int j = 0; j < 4; ++j) acc[i][j] = (f32x4){0.f, 0.f, 0.f, 0.f};

    uint srow[4], soff[4];
#pragma unroll
    for (int i = 0; i < 4; ++i) {
        uint p = (uint)i * 256u + (uint)t;
        uint row = p >> 3, pc = p & 7;
        srow[i] = row;
        soff[i] = (pc ^ (row & 7u)) * 8u;
    }

#pragma unroll 1
    for (int s = 0; s < 6; ++s) {
        const int src = (s >= 3) ? 1 : 0;
        const int combo = s - src * 3;               // 0 hh, 1 hl, 2 lh
        const unsigned short* Ap = src ? ((combo == 2) ? Xlo : Xhi)
                                       : ((combo == 2) ? Glo : Ghi);
        const unsigned short* Wp = src ? ((combo == 1) ? WRlo : WRhi)
                                       : ((combo == 1) ? WLlo : WLhi);
#pragma unroll 1
        for (int kt = 0; kt < 8; ++kt) {
            const int kb = kt * 64;
#pragma unroll
            for (int i = 0; i < 4; ++i) {
                const unsigned short* ga =
                    Ap + (size_t)(m0 + srow[i]) * DIM + kb + soff[i];
                const unsigned short* gw =
                    Wp + (size_t)(n0 + srow[i]) * DIM + kb + soff[i];
                uint p16 = ((uint)i * 256u + (uint)t) * 16u;
                gload16(ga, (char*)sA + p16);
                gload16(gw, (char*)sW + p16);
            }
            __syncthreads();
#pragma unroll
            for (int ks = 0; ks < 2; ++ks) {
                s16x8 af[4], wf[4];
#pragma unroll
                for (int i = 0; i < 4; ++i) {
                    int arow = wr * 64 + i * 16 + lr;
                    int off = arow * 128 + 16 * ((ks * 4 + lq) ^ (arow & 7));
                    af[i] = *(const s16x8*)((const char*)sA + off);
                }
#pragma unroll
                for (int j = 0; j < 4; ++j) {
                    int wrow = wc * 64 + j * 16 + lr;
                    int off = wrow * 128 + 16 * ((ks * 4 + lq) ^ (wrow & 7));
                    wf[j] = *(const s16x8*)((const char*)sW + off);
                }
#pragma unroll
                for (int i = 0; i < 4; ++i)
#pragma unroll
                    for (int j = 0; j < 4; ++j)
                        acc[i][j] = __builtin_amdgcn_mfma_f32_16x16x32_bf16(
                            af[i], wf[j], acc[i][j], 0, 0, 0);
            }
            __syncthreads();
        }
    }

#pragma unroll
    for (int i = 0; i < 4; ++i) {
        const int r0 = m0 + wr * 64 + i * 16 + lq * 4;
#pragma unroll
        for (int j = 0; j < 4; ++j) {
            const int cc = n0 + wc * 64 + j * 16 + lr;
            const float bv = bias[cc];
#pragma unroll
            for (int r = 0; r < 4; ++r) {
                float v = acc[i][j][r] + bv;
                C[(size_t)(r0 + r) * DIM + cc] = fmaxf(v, 0.f);
            }
        }
    }
}

// ---------------------------------------------------------------------------
// 5. Fused pool: topk scores + rank + gate/split-write + readout + edge remap
//    One block per graph. newid kept in LDS (masked edges never read it).
// ---------------------------------------------------------------------------
template<int NPER, int KEEP, bool REMAP, bool INIT>
__global__ void __launch_bounds__(256)
pool_fused(const float* __restrict__ Y, const float* __restrict__ p,
           unsigned short* __restrict__ Xhi, unsigned short* __restrict__ Xlo,
           const int* __restrict__ es, const int* __restrict__ ed,
           const float* __restrict__ em,
           int* __restrict__ nes, int* __restrict__ ned, float* __restrict__ nem,
           float* __restrict__ H)
{
    const int g = blockIdx.x;
    const int t = threadIdx.x;
    const int wave = t >> 6, lane = t & 63;
    __shared__ float ssc[NPER];
    __shared__ float spnorm;
    __shared__ int   perm[KEEP];
    __shared__ float sgate[KEEP];
    __shared__ int   lnewid[NPER];

    // ---- p norm (wave 0) ----
    if (wave == 0) {
        float v = 0.f;
#pragma unroll
        for (int i = 0; i < 8; ++i) { float x = p[lane + i * 64]; v = fmaf(x, x, v); }
#pragma unroll
        for (int off = 32; off; off >>= 1) v += __shfl_down(v, off);
        if (lane == 0) spnorm = sqrtf(v);
    }
    // ---- scores: dot(Y[row], p), 4 waves stride rows ----
    for (int nl = wave; nl < NPER; nl += 4) {
        const float* yr = Y + (size_t)(g * NPER + nl) * DIM;
        float v = 0.f;
#pragma unroll
        for (int i = 0; i < 8; ++i) v = fmaf(yr[lane + i * 64], p[lane + i * 64], v);
#pragma unroll
        for (int off = 32; off; off >>= 1) v += __shfl_down(v, off);
        if (lane == 0) ssc[nl] = v;
    }
    __syncthreads();
    float s = 0.f;
    if (t < NPER) s = tanhf(ssc[t] / spnorm);
    __syncthreads();
    if (t < NPER) ssc[t] = s;
    __syncthreads();
    if (t < NPER) {
        int r = 0;
        for (int j = 0; j < NPER; ++j) {
            float sj = ssc[j];
            r += (sj > s) || (sj == s && j < t);
        }
        lnewid[t] = (r < KEEP) ? (g * KEEP + r) : -1;
        if (r < KEEP) { perm[r] = t; sgate[r] = s; }
    }
    __syncthreads();

    // ---- gather selected rows: gate, split-write, running max/sum ----
    float mx0 = -1e30f, mx1 = -1e30f, sm0 = 0.f, sm1 = 0.f;
    for (int r = 0; r < KEEP; ++r) {
        const float2 v = ((const float2*)(Y + (size_t)(g * NPER + perm[r]) * DIM))[t];
        const float sv = sgate[r];
        float a = v.x * sv, b = v.y * sv;
        mx0 = fmaxf(mx0, a); mx1 = fmaxf(mx1, b);
        sm0 += a; sm1 += b;
        unsigned short ha, la, hb, lb;
        splitf(a, ha, la); splitf(b, hb, lb);
        size_t o = (size_t)(g * KEEP + r) * DIM + 2 * t;
        *(uint*)(Xhi + o) = pk2(ha, hb);
        *(uint*)(Xlo + o) = pk2(la, lb);
    }
    {   // readout: thread t owns dims 2t, 2t+1
        const size_t o = (size_t)g * 1024;
        const float me0 = sm0 / (float)KEEP, me1 = sm1 / (float)KEEP;
        if (INIT) {
            H[o + 2*t]       = mx0; H[o + 2*t + 1]       = mx1;
            H[o + 512 + 2*t] = me0; H[o + 512 + 2*t + 1] = me1;
        } else {
            H[o + 2*t]       += mx0; H[o + 2*t + 1]       += mx1;
            H[o + 512 + 2*t] += me0; H[o + 512 + 2*t + 1] += me1;
        }
    }

    // ---- edge remap (LDS newid; masked edges never read ids) ----
    if (REMAP) {
        const int eb = g * EPG;
        for (int e = t; e < EPG; e += 256) {
            const float m = em ? em[eb + e] : 1.f;
            int sN = -1, dN = -1;
            if (m > 0.f) {
                sN = lnewid[es[eb + e] - g * NPER];
                dN = lnewid[ed[eb + e] - g * NPER];
            }
            const bool v = (m > 0.f) && (sN >= 0) && (dN >= 0);
            nes[eb + e] = v ? sN : 0;
            ned[eb + e] = v ? dN : 0;
            nem[eb + e] = v ? 1.f : 0.f;
        }
    }
}

// ---------------------------------------------------------------------------
// 6. Fused MLP head
// ---------------------------------------------------------------------------
__global__ void __launch_bounds__(256)
mlp_fused(const float* __restrict__ H,
          const float* __restrict__ lw1, const float* __restrict__ lb1,
          const float* __restrict__ lw2, const float* __restrict__ lb2,
          const float* __restrict__ lw3, const float* __restrict__ lb3,
          const float* __restrict__ lw4, const float* __restrict__ lb4,
          const float* __restrict__ lw5, const float* __restrict__ lb5,
          float* __restrict__ out)
{
    __shared__ float h0[2][1024];
    __shared__ float y1[2][512];
    __shared__ float y2[2][256];
    __shared__ float y3[2][128];
    __shared__ float y4[2][64];
    const int t = threadIdx.x;
    const int r0 = blockIdx.x * 2;

    {
        float4 a = *(const float4*)&H[(size_t)r0 * 1024 + t * 4];
        float4 b = *(const float4*)&H[(size_t)(r0 + 1) * 1024 + t * 4];
        *(float4*)&h0[0][t * 4] = a;
        *(float4*)&h0[1][t * 4] = b;
    }
    __syncthreads();
    {
        float a00 = 0.f, a01 = 0.f, a10 = 0.f, a11 = 0.f;
        const int c = t * 2;
#pragma unroll 4
        for (int k = 0; k < 1024; ++k) {
            float2 wv = *(const float2*)&lw1[(size_t)k * 512 + c];
            float x0 = h0[0][k], x1 = h0[1][k];
            a00 = fmaf(x0, wv.x, a00); a01 = fmaf(x0, wv.y, a01);
            a10 = fmaf(x1, wv.x, a10); a11 = fmaf(x1, wv.y, a11);
        }
        y1[0][c]     = fmaxf(a00 + lb1[c], 0.f);
        y1[0][c + 1] = fmaxf(a01 + lb1[c + 1], 0.f);
        y1[1][c]     = fmaxf(a10 + lb1[c], 0.f);
        y1[1][c + 1] = fmaxf(a11 + lb1[c + 1], 0.f);
    }
    __syncthreads();
    {
        float a0 = 0.f, a1 = 0.f;
#pragma unroll 4
        for (int k = 0; k < 512; ++k) {
            float wv = lw2[(size_t)k * 256 + t];
            a0 = fmaf(y1[0][k], wv, a0);
            a1 = fmaf(y1[1][k], wv, a1);
        }
        y2[0][t] = fmaxf(a0 + lb2[t], 0.f);
        y2[1][t] = fmaxf(a1 + lb2[t], 0.f);
    }
    __syncthreads();
    if (t < 128) {
        float a0 = 0.f, a1 = 0.f;
#pragma unroll 4
        for (int k = 0; k < 256; ++k) {
            float wv = lw3[(size_t)k * 128 + t];
            a0 = fmaf(y2[0][k], wv, a0);
            a1 = fmaf(y2[1][k], wv, a1);
        }
        y3[0][t] = fmaxf(a0 + lb3[t], 0.f);
        y3[1][t] = fmaxf(a1 + lb3[t], 0.f);
    }
    __syncthreads();
    if (t < 64) {
        float a0 = 0.f, a1 = 0.f;
#pragma unroll 4
        for (int k = 0; k < 128; ++k) {
            float wv = lw4[(size_t)k * 64 + t];
            a0 = fmaf(y3[0][k], wv, a0);
            a1 = fmaf(y3[1][k], wv, a1);
        }
        y4[0][t] = fmaxf(a0 + lb4[t], 0.f);
        y4[1][t] = fmaxf(a1 + lb4[t], 0.f);
    }
    __syncthreads();
    const int wv = t >> 6, ln = t & 63;
    if (wv < 2) {
        float v = y4[wv][ln] * lw5[ln];
#pragma unroll
        for (int off = 32; off; off >>= 1) v += __shfl_down(v, off);
        if (ln == 0) out[r0 + wv] = 1.f / (1.f + expf(-(v + lb5[0])));
    }
}

// ---------------------------------------------------------------------------
extern "C" void kernel_launch(void* const* d_in, const int* in_sizes, int n_in,
                              void* d_out, int out_size, void* d_ws, size_t ws_size,
                              hipStream_t stream)
{
    const int*   x_ids = (const int*)d_in[0];
    const int*   esrc  = (const int*)d_in[1];
    const int*   edst  = (const int*)d_in[2];
    const float* emb   = (const float*)d_in[3];
    const float* w1l = (const float*)d_in[4],  *b1l = (const float*)d_in[5],  *w1r = (const float*)d_in[6];
    const float* w2l = (const float*)d_in[7],  *b2l = (const float*)d_in[8],  *w2r = (const float*)d_in[9];
    const float* w3l = (const float*)d_in[10], *b3l = (const float*)d_in[11], *w3r = (const float*)d_in[12];
    const float* p1  = (const float*)d_in[13];
    const float* p2  = (const float*)d_in[14];
    const float* p3  = (const float*)d_in[15];
    const float* lw1 = (const float*)d_in[16], *lb1 = (const float*)d_in[17];
    const float* lw2 = (const float*)d_in[18], *lb2 = (const float*)d_in[19];
    const float* lw3 = (const float*)d_in[20], *lb3 = (const float*)d_in[21];
    const float* lw4 = (const float*)d_in[22], *lb4 = (const float*)d_in[23];
    const float* lw5 = (const float*)d_in[24], *lb5 = (const float*)d_in[25];
    float* out = (float*)d_out;

    // ---- workspace layout ----
    const size_t PL = (size_t)65536 * DIM;
    unsigned short* Xhi = (unsigned short*)d_ws;
    unsigned short* Xlo = Xhi + PL;
    unsigned short* Ghi = Xlo + PL;
    unsigned short* Glo = Ghi + PL;
    float* Cc = (float*)(Glo + PL);
    float* H  = Cc + PL;
    int*   ES2 = (int*)(H + (size_t)1024 * 1024);
    int*   ED2 = ES2 + ETOT;
    float* EM2 = (float*)(ED2 + ETOT);
    int*   ES3 = (int*)(EM2 + ETOT);
    int*   ED3 = ES3 + ETOT;
    float* EM3 = (float*)(ED3 + ETOT);
    unsigned short* WT = (unsigned short*)(EM3 + ETOT);  // 12 planes x 512*512
    const size_t WSZ = (size_t)DIM * DIM;
    unsigned short *w1lh = WT + 0*WSZ,  *w1ll = WT + 1*WSZ;
    unsigned short *w1rh = WT + 2*WSZ,  *w1rl = WT + 3*WSZ;
    unsigned short *w2lh = WT + 4*WSZ,  *w2ll = WT + 5*WSZ;
    unsigned short *w2rh = WT + 6*WSZ,  *w2rl = WT + 7*WSZ;
    unsigned short *w3lh = WT + 8*WSZ,  *w3ll = WT + 9*WSZ;
    unsigned short *w3rh = WT + 10*WSZ, *w3rl = WT + 11*WSZ;

    // ---- weight conversion (one launch) ----
    WPtrs wp;
    wp.w[0] = w1l; wp.w[1] = w1r; wp.w[2] = w2l;
    wp.w[3] = w2r; wp.w[4] = w3l; wp.w[5] = w3r;
    split_wT_all<<<6 * 256, 256, 0, stream>>>(wp, WT);

    // ---- layer 1 ----
    gather_split<<<16384, 256, 0, stream>>>(x_ids, emb, Xhi, Xlo);
    agg_lds4<64><<<BG * 4, 256, 0, stream>>>(Xhi, Xlo, esrc, edst, nullptr, Ghi, Glo);
    gemm_sage<<<(65536/128)*4, 256, 0, stream>>>(Ghi, Glo, w1lh, w1ll,
                                                 Xhi, Xlo, w1rh, w1rl, b1l, Cc, 65536);
    pool_fused<64, KP1, true, true><<<BG, 256, 0, stream>>>(
        Cc, p1, Xhi, Xlo, esrc, edst, nullptr, ES2, ED2, EM2, H);

    // ---- layer 2 ----
    agg_lds4<KP1><<<BG * 4, 256, 0, stream>>>(Xhi, Xlo, ES2, ED2, EM2, Ghi, Glo);
    gemm_sage<<<(53248/128)*4, 256, 0, stream>>>(Ghi, Glo, w2lh, w2ll,
                                                 Xhi, Xlo, w2rh, w2rl, b2l, Cc, 53248);
    pool_fused<KP1, KP2, true, false><<<BG, 256, 0, stream>>>(
        Cc, p2, Xhi, Xlo, ES2, ED2, EM2, ES3, ED3, EM3, H);

    // ---- layer 3 ----
    agg_lds4<KP2><<<BG * 4, 256, 0, stream>>>(Xhi, Xlo, ES3, ED3, EM3, Ghi, Glo);
    gemm_sage<<<(43008/128)*4, 256, 0, stream>>>(Ghi, Glo, w3lh, w3ll,
                                                 Xhi, Xlo, w3rh, w3rl, b3l, Cc, 43008);
    pool_fused<KP2, KP3, false, false><<<BG, 256, 0, stream>>>(
        Cc, p3, Xhi, Xlo, nullptr, nullptr, nullptr, nullptr, nullptr, nullptr, H);

    // ---- fused MLP head ----
    mlp_fused<<<512, 256, 0, stream>>>(H, lw1, lb1, lw2, lb2, lw3, lb3,
                                       lw4, lb4, lw5, lb5, out);
}

// Round 8
// 1170.440 us; speedup vs baseline: 1.4397x; 1.1155x over previous
//
#include <hip/hip_runtime.h>
#include <math.h>

// Problem constants
#define BG 1024
#define EPG 512
#define ETOT (BG*EPG)
#define DIM 512
#define KP1 52
#define KP2 42
#define KP3 34
#define OFS 80   // stride of per-graph offset tables

typedef unsigned int uint;
typedef short s16x8 __attribute__((ext_vector_type(8)));
typedef float f32x4 __attribute__((ext_vector_type(4)));

// ---------------- bf16 split helpers ----------------
__device__ __forceinline__ unsigned short f2b(float x) {
    uint u = __float_as_uint(x);
    u = u + 0x7fffu + ((u >> 16) & 1u);
    return (unsigned short)(u >> 16);
}
__device__ __forceinline__ float b2f(unsigned short h) {
    return __uint_as_float(((uint)h) << 16);
}
__device__ __forceinline__ void splitf(float x, unsigned short& h, unsigned short& l) {
    h = f2b(x);
    l = f2b(x - b2f(h));
}
__device__ __forceinline__ uint pk2(unsigned short a, unsigned short b) {
    return (uint)a | ((uint)b << 16);
}

__device__ __forceinline__ void gload16(const void* g, void* l) {
    __builtin_amdgcn_global_load_lds(
        (const __attribute__((address_space(1))) void*)g,
        (__attribute__((address_space(3))) void*)l, 16, 0, 0);
}

// ---------------------------------------------------------------------------
// 1. Gather + split: X[i,:] = emb[ids[i],:]  ->  hi/lo bf16 planes
// ---------------------------------------------------------------------------
__global__ void __launch_bounds__(256)
gather_split(const int* __restrict__ ids, const float* __restrict__ emb,
             unsigned short* __restrict__ Xhi, unsigned short* __restrict__ Xlo)
{
    int tid = blockIdx.x * 256 + threadIdx.x;
    int row = tid >> 6;
    int c8  = (tid & 63) * 8;
    const float4* s = (const float4*)(emb + (size_t)ids[row] * DIM + c8);
    float4 v0 = s[0], v1 = s[1];
    float vs[8] = {v0.x,v0.y,v0.z,v0.w,v1.x,v1.y,v1.z,v1.w};
    unsigned short h[8], l[8];
#pragma unroll
    for (int i = 0; i < 8; ++i) splitf(vs[i], h[i], l[i]);
    uint4 H, L;
    H.x = pk2(h[0],h[1]); H.y = pk2(h[2],h[3]); H.z = pk2(h[4],h[5]); H.w = pk2(h[6],h[7]);
    L.x = pk2(l[0],l[1]); L.y = pk2(l[2],l[3]); L.z = pk2(l[4],l[5]); L.w = pk2(l[6],l[7]);
    *(uint4*)(Xhi + (size_t)row * DIM + c8) = H;
    *(uint4*)(Xlo + (size_t)row * DIM + c8) = L;
}

// ---------------------------------------------------------------------------
// 2. Weight convert, all 6 weights in one launch
// ---------------------------------------------------------------------------
struct WPtrs { const float* w[6]; };

__global__ void __launch_bounds__(256)
split_wT_all(WPtrs p, unsigned short* __restrict__ WT)
{
    const int wi = blockIdx.x >> 8;
    const int bb = blockIdx.x & 255;
    const float* W = p.w[wi];
    unsigned short* Thi = WT + (size_t)(2 * wi) * DIM * DIM;
    unsigned short* Tlo = Thi + (size_t)DIM * DIM;
    __shared__ float tl[32][33];
    const int t  = threadIdx.x;
    const int bx = bb & 15;
    const int by = bb >> 4;
    const int lx = t & 31, ly = t >> 5;
    for (int r = ly; r < 32; r += 8)
        tl[r][lx] = W[(size_t)(by*32 + r) * DIM + bx*32 + lx];
    __syncthreads();
    for (int r = ly; r < 32; r += 8) {
        float v = tl[lx][r];
        unsigned short h, l; splitf(v, h, l);
        size_t o = (size_t)(bx*32 + r) * DIM + by*32 + lx;
        Thi[o] = h; Tlo[o] = l;
    }
}

// ---------------------------------------------------------------------------
// 3. Layer-1 edge sort: counting sort by local dst, packed (dst<<16|src)
// ---------------------------------------------------------------------------
__global__ void __launch_bounds__(256)
sort_edges1(const int* __restrict__ esrc, const int* __restrict__ edst,
            uint* __restrict__ SE, int* __restrict__ OF)
{
    const int g = blockIdx.x;
    const int t = threadIdx.x;
    __shared__ int ld[EPG];
    __shared__ int ls[EPG];
    __shared__ int cnt4[4][64];
    __shared__ int offs[65];
    const int eb = g * EPG;
    for (int e = t; e < EPG; e += 256) {
        ld[e] = edst[eb + e] - g * 64;
        ls[e] = esrc[eb + e] - g * 64;
    }
    __syncthreads();
    {
        const int d = t & 63, q = t >> 6;
        int c = 0;
        for (int e = q * 128; e < q * 128 + 128; ++e) c += (ld[e] == d);
        cnt4[q][d] = c;
    }
    __syncthreads();
    if (t == 0) {
        int s = 0;
        for (int i = 0; i < 64; ++i) {
            offs[i] = s;
            s += cnt4[0][i] + cnt4[1][i] + cnt4[2][i] + cnt4[3][i];
        }
        offs[64] = s;
    }
    __syncthreads();
    {
        const int d = t & 63, q = t >> 6;
        int w = offs[d];
        for (int q2 = 0; q2 < q; ++q2) w += cnt4[q2][d];
        for (int e = q * 128; e < q * 128 + 128; ++e)
            if (ld[e] == d) SE[(size_t)g * EPG + (w++)] = ((uint)d << 16) | (uint)ls[e];
    }
    if (t <= 64) OF[g * OFS + t] = offs[t];
}

// ---------------------------------------------------------------------------
// 4. Mean aggregation from pre-sorted edge lists, column-sliced
// ---------------------------------------------------------------------------
template<int NPER>
__global__ void __launch_bounds__(256, 4)
agg_sorted(const unsigned short* __restrict__ Xhi, const unsigned short* __restrict__ Xlo,
           const uint* __restrict__ SE, const int* __restrict__ OF,
           unsigned short* __restrict__ Ghi, unsigned short* __restrict__ Glo)
{
    const int g  = blockIdx.x >> 2;
    const int c0 = (blockIdx.x & 3) * 128;
    const int t  = threadIdx.x;
    __shared__ __align__(16) unsigned short xs[NPER * 256];
    __shared__ uint el[EPG];
    __shared__ int offs[NPER + 1];

    // stage node-row slices (linear dest, 16B gload)
    for (int s = t; s < NPER * 32; s += 256) {
        const int row  = s >> 5;
        const int half = (s >> 4) & 1;
        const int c8   = (s & 15) * 8;
        const unsigned short* src =
            (half ? Xlo : Xhi) + (size_t)(g * NPER + row) * DIM + c0 + c8;
        gload16(src, (char*)xs + (size_t)s * 16);
    }
    if (t <= NPER) offs[t] = OF[g * OFS + t];
    __syncthreads();                 // offs ready; vmcnt(0) drained by barrier
    const int cnt = offs[NPER];
    for (int e = t; e < cnt; e += 256) el[e] = SE[(size_t)g * EPG + e];
    __syncthreads();

    const int ch = (t & 31) * 4;
    const int d0 = t >> 5;
    for (int d = d0; d < NPER; d += 8) {
        const int cA = offs[d], cB = offs[d + 1];
        float s0 = 0.f, s1 = 0.f, s2 = 0.f, s3 = 0.f;
        for (int j = cA; j < cB; ++j) {
            const int base = (int)(el[j] & 0xffffu) * 256 + ch;
            ushort4 h = *(const ushort4*)&xs[base];
            ushort4 l = *(const ushort4*)&xs[base + 128];
            s0 += b2f(h.x) + b2f(l.x);
            s1 += b2f(h.y) + b2f(l.y);
            s2 += b2f(h.z) + b2f(l.z);
            s3 += b2f(h.w) + b2f(l.w);
        }
        const float den = fmaxf((float)(cB - cA), 1.0f);
        s0 /= den; s1 /= den; s2 /= den; s3 /= den;
        unsigned short h0,h1,h2,h3,l0,l1,l2,l3;
        splitf(s0,h0,l0); splitf(s1,h1,l1); splitf(s2,h2,l2); splitf(s3,h3,l3);
        const size_t wo = (size_t)(g * NPER + d) * DIM + c0 + ch;
        *(uint2*)(Ghi + wo) = make_uint2(pk2(h0,h1), pk2(h2,h3));
        *(uint2*)(Glo + wo) = make_uint2(pk2(l0,l1), pk2(l2,l3));
    }
}

// ---------------------------------------------------------------------------
// 5. Split-bf16 MFMA GEMM + fused per-row score partials (y . p per N-block)
// ---------------------------------------------------------------------------
__global__ void __launch_bounds__(256)
gemm_sage(const unsigned short* __restrict__ Ghi, const unsigned short* __restrict__ Glo,
          const unsigned short* __restrict__ WLhi, const unsigned short* __restrict__ WLlo,
          const unsigned short* __restrict__ Xhi, const unsigned short* __restrict__ Xlo,
          const unsigned short* __restrict__ WRhi, const unsigned short* __restrict__ WRlo,
          const float* __restrict__ bias, const float* __restrict__ pvec,
          float* __restrict__ C, float* __restrict__ SC4, int M)
{
    __shared__ unsigned short sA[128 * 64];
    __shared__ unsigned short sW[128 * 64];
    __shared__ float scp[128][2];

    const int t = threadIdx.x;
    const uint nwg = gridDim.x;
    const uint q8  = nwg >> 3;
    const uint bid = blockIdx.x;
    const uint sw  = (bid & 7) * q8 + (bid >> 3);
    const int  m0  = (int)(sw >> 2) * 128;
    const int  n0  = (int)(sw & 3) * 128;

    const int l  = t & 63;
    const int w  = t >> 6;
    const int wr = w >> 1;
    const int wc = w & 1;
    const int lr = l & 15;
    const int lq = l >> 4;

    f32x4 acc[4][4];
#pragma unroll
    for (int i = 0; i < 4; ++i)
#pragma unroll
        for (int j = 0; j < 4; ++j) acc[i][j] = (f32x4){0.f, 0.f, 0.f, 0.f};

    uint srow[4], soff[4];
#pragma unroll
    for (int i = 0; i < 4; ++i) {
        uint p = (uint)i * 256u + (uint)t;
        uint row = p >> 3, pc = p & 7;
        srow[i] = row;
        soff[i] = (pc ^ (row & 7u)) * 8u;
    }

#pragma unroll 1
    for (int s = 0; s < 6; ++s) {
        const int src = (s >= 3) ? 1 : 0;
        const int combo = s - src * 3;               // 0 hh, 1 hl, 2 lh
        const unsigned short* Ap = src ? ((combo == 2) ? Xlo : Xhi)
                                       : ((combo == 2) ? Glo : Ghi);
        const unsigned short* Wp = src ? ((combo == 1) ? WRlo : WRhi)
                                       : ((combo == 1) ? WLlo : WLhi);
#pragma unroll 1
        for (int kt = 0; kt < 8; ++kt) {
            const int kb = kt * 64;
#pragma unroll
            for (int i = 0; i < 4; ++i) {
                const unsigned short* ga =
                    Ap + (size_t)(m0 + srow[i]) * DIM + kb + soff[i];
                const unsigned short* gw =
                    Wp + (size_t)(n0 + srow[i]) * DIM + kb + soff[i];
                uint p16 = ((uint)i * 256u + (uint)t) * 16u;
                gload16(ga, (char*)sA + p16);
                gload16(gw, (char*)sW + p16);
            }
            __syncthreads();
#pragma unroll
            for (int ks = 0; ks < 2; ++ks) {
                s16x8 af[4], wf[4];
#pragma unroll
                for (int i = 0; i < 4; ++i) {
                    int arow = wr * 64 + i * 16 + lr;
                    int off = arow * 128 + 16 * ((ks * 4 + lq) ^ (arow & 7));
                    af[i] = *(const s16x8*)((const char*)sA + off);
                }
#pragma unroll
                for (int j = 0; j < 4; ++j) {
                    int wrow = wc * 64 + j * 16 + lr;
                    int off = wrow * 128 + 16 * ((ks * 4 + lq) ^ (wrow & 7));
                    wf[j] = *(const s16x8*)((const char*)sW + off);
                }
#pragma unroll
                for (int i = 0; i < 4; ++i)
#pragma unroll
                    for (int j = 0; j < 4; ++j)
                        acc[i][j] = __builtin_amdgcn_mfma_f32_16x16x32_bf16(
                            af[i], wf[j], acc[i][j], 0, 0, 0);
            }
            __syncthreads();
        }
    }

    // epilogue: bias + relu + C store + per-row score partial (cols of this block)
    float part[4][4];
#pragma unroll
    for (int i = 0; i < 4; ++i)
#pragma unroll
        for (int r = 0; r < 4; ++r) part[i][r] = 0.f;

#pragma unroll
    for (int i = 0; i < 4; ++i) {
        const int r0 = m0 + wr * 64 + i * 16 + lq * 4;
#pragma unroll
        for (int j = 0; j < 4; ++j) {
            const int cc = n0 + wc * 64 + j * 16 + lr;
            const float bv = bias[cc];
            const float pv = pvec[cc];
#pragma unroll
            for (int r = 0; r < 4; ++r) {
                float v = fmaxf(acc[i][j][r] + bv, 0.f);
                C[(size_t)(r0 + r) * DIM + cc] = v;
                part[i][r] = fmaf(v, pv, part[i][r]);
            }
        }
    }
    // reduce over the 16 lr lanes (same lq group)
#pragma unroll
    for (int o = 1; o < 16; o <<= 1)
#pragma unroll
        for (int i = 0; i < 4; ++i)
#pragma unroll
            for (int r = 0; r < 4; ++r)
                part[i][r] += __shfl_xor(part[i][r], o);
    if (lr == 0) {
#pragma unroll
        for (int i = 0; i < 4; ++i)
#pragma unroll
            for (int r = 0; r < 4; ++r)
                scp[wr * 64 + i * 16 + lq * 4 + r][wc] = part[i][r];
    }
    __syncthreads();
    if (t < 128)
        SC4[(size_t)(m0 + t) * 4 + (n0 >> 7)] = scp[t][0] + scp[t][1];
}

// ---------------------------------------------------------------------------
// 6. Fused pool: scores from SC4 + rank + gate/split-write + readout
//    + sorted-edge remap for next layer (counting sort in LDS).
// ---------------------------------------------------------------------------
template<int NPER, int KEEP, bool REMAP, bool INIT>
__global__ void __launch_bounds__(256)
pool_fused(const float* __restrict__ Y, const float* __restrict__ p,
           const float* __restrict__ SC4,
           unsigned short* __restrict__ Xhi, unsigned short* __restrict__ Xlo,
           const uint* __restrict__ SEp, const int* __restrict__ OFp,
           uint* __restrict__ SEn, int* __restrict__ OFn,
           float* __restrict__ H)
{
    const int g = blockIdx.x;
    const int t = threadIdx.x;
    const int wave = t >> 6, lane = t & 63;
    __shared__ float ssc[NPER];
    __shared__ float spnorm;
    __shared__ int   perm[KEEP];
    __shared__ float sgate[KEEP];
    __shared__ int   lnewid[NPER];
    __shared__ uint  eprev[EPG];
    __shared__ uint  enew[EPG];
    __shared__ int   cnt4[4][64];
    __shared__ int   offs[KEEP + 1];

    // ---- ||p|| (wave 0) ----
    if (wave == 0) {
        float v = 0.f;
#pragma unroll
        for (int i = 0; i < 8; ++i) { float x = p[lane + i * 64]; v = fmaf(x, x, v); }
#pragma unroll
        for (int off = 32; off; off >>= 1) v += __shfl_down(v, off);
        if (lane == 0) spnorm = sqrtf(v);
    }
    __syncthreads();
    // ---- scores from precomputed partials ----
    if (t < NPER) {
        const float* s4 = SC4 + (size_t)(g * NPER + t) * 4;
        float raw = s4[0] + s4[1] + s4[2] + s4[3];
        ssc[t] = tanhf(raw / spnorm);
    }
    __syncthreads();
    if (t < NPER) {
        const float s = ssc[t];
        int r = 0;
        for (int j = 0; j < NPER; ++j) {
            float sj = ssc[j];
            r += (sj > s) || (sj == s && j < t);
        }
        lnewid[t] = (r < KEEP) ? r : -1;      // LOCAL new id
        if (r < KEEP) { perm[r] = t; sgate[r] = s; }
    }
    __syncthreads();

    // ---- gather selected rows: gate, split-write, running max/sum ----
    float mx0 = -1e30f, mx1 = -1e30f, sm0 = 0.f, sm1 = 0.f;
    for (int r = 0; r < KEEP; ++r) {
        const float2 v = ((const float2*)(Y + (size_t)(g * NPER + perm[r]) * DIM))[t];
        const float sv = sgate[r];
        float a = v.x * sv, b = v.y * sv;
        mx0 = fmaxf(mx0, a); mx1 = fmaxf(mx1, b);
        sm0 += a; sm1 += b;
        unsigned short ha, la, hb, lb;
        splitf(a, ha, la); splitf(b, hb, lb);
        size_t o = (size_t)(g * KEEP + r) * DIM + 2 * t;
        *(uint*)(Xhi + o) = pk2(ha, hb);
        *(uint*)(Xlo + o) = pk2(la, lb);
    }
    {   // readout: thread t owns dims 2t, 2t+1
        const size_t o = (size_t)g * 1024;
        const float me0 = sm0 / (float)KEEP, me1 = sm1 / (float)KEEP;
        if (INIT) {
            H[o + 2*t]       = mx0; H[o + 2*t + 1]       = mx1;
            H[o + 512 + 2*t] = me0; H[o + 512 + 2*t + 1] = me1;
        } else {
            H[o + 2*t]       += mx0; H[o + 2*t + 1]       += mx1;
            H[o + 512 + 2*t] += me0; H[o + 512 + 2*t + 1] += me1;
        }
    }

    // ---- remap + counting-sort the surviving edges for next layer ----
    if constexpr (REMAP) {
        const int cntp = OFp[g * OFS + NPER];
        for (int e = t; e < cntp; e += 256)
            eprev[e] = SEp[(size_t)g * EPG + e];
        __syncthreads();
        for (int e = t; e < cntp; e += 256) {
            const uint pk = eprev[e];
            const int ns = lnewid[pk & 0xffffu];
            const int nd = lnewid[pk >> 16];
            enew[e] = (ns >= 0 && nd >= 0)
                ? (((uint)nd << 16) | (uint)ns) : 0xFFFFFFFFu;
        }
        __syncthreads();
        {
            const int d = t & 63, q = t >> 6;
            int c = 0;
            const int e0 = q * 128;
            const int e1 = (e0 + 128 < cntp) ? e0 + 128 : cntp;
            for (int e = e0; e < e1; ++e) c += ((enew[e] >> 16) == (uint)d);
            cnt4[q][d] = c;
        }
        __syncthreads();
        if (t == 0) {
            int s = 0;
            for (int i = 0; i < KEEP; ++i) {
                offs[i] = s;
                s += cnt4[0][i] + cnt4[1][i] + cnt4[2][i] + cnt4[3][i];
            }
            offs[KEEP] = s;
        }
        __syncthreads();
        {
            const int d = t & 63, q = t >> 6;
            if (d < KEEP) {
                int w = offs[d];
                for (int q2 = 0; q2 < q; ++q2) w += cnt4[q2][d];
                const int e0 = q * 128;
                const int e1 = (e0 + 128 < cntp) ? e0 + 128 : cntp;
                for (int e = e0; e < e1; ++e)
                    if ((enew[e] >> 16) == (uint)d)
                        SEn[(size_t)g * EPG + (w++)] = enew[e];
            }
        }
        if (t <= KEEP) OFn[g * OFS + t] = offs[t];
    }
}

// ---------------------------------------------------------------------------
// 7. Fused MLP head
// ---------------------------------------------------------------------------
__global__ void __launch_bounds__(256)
mlp_fused(const float* __restrict__ H,
          const float* __restrict__ lw1, const float* __restrict__ lb1,
          const float* __restrict__ lw2, const float* __restrict__ lb2,
          const float* __restrict__ lw3, const float* __restrict__ lb3,
          const float* __restrict__ lw4, const float* __restrict__ lb4,
          const float* __restrict__ lw5, const float* __restrict__ lb5,
          float* __restrict__ out)
{
    __shared__ float h0[2][1024];
    __shared__ float y1[2][512];
    __shared__ float y2[2][256];
    __shared__ float y3[2][128];
    __shared__ float y4[2][64];
    const int t = threadIdx.x;
    const int r0 = blockIdx.x * 2;

    {
        float4 a = *(const float4*)&H[(size_t)r0 * 1024 + t * 4];
        float4 b = *(const float4*)&H[(size_t)(r0 + 1) * 1024 + t * 4];
        *(float4*)&h0[0][t * 4] = a;
        *(float4*)&h0[1][t * 4] = b;
    }
    __syncthreads();
    {
        float a00 = 0.f, a01 = 0.f, a10 = 0.f, a11 = 0.f;
        const int c = t * 2;
#pragma unroll 4
        for (int k = 0; k < 1024; ++k) {
            float2 wv = *(const float2*)&lw1[(size_t)k * 512 + c];
            float x0 = h0[0][k], x1 = h0[1][k];
            a00 = fmaf(x0, wv.x, a00); a01 = fmaf(x0, wv.y, a01);
            a10 = fmaf(x1, wv.x, a10); a11 = fmaf(x1, wv.y, a11);
        }
        y1[0][c]     = fmaxf(a00 + lb1[c], 0.f);
        y1[0][c + 1] = fmaxf(a01 + lb1[c + 1], 0.f);
        y1[1][c]     = fmaxf(a10 + lb1[c], 0.f);
        y1[1][c + 1] = fmaxf(a11 + lb1[c + 1], 0.f);
    }
    __syncthreads();
    {
        float a0 = 0.f, a1 = 0.f;
#pragma unroll 4
        for (int k = 0; k < 512; ++k) {
            float wv = lw2[(size_t)k * 256 + t];
            a0 = fmaf(y1[0][k], wv, a0);
            a1 = fmaf(y1[1][k], wv, a1);
        }
        y2[0][t] = fmaxf(a0 + lb2[t], 0.f);
        y2[1][t] = fmaxf(a1 + lb2[t], 0.f);
    }
    __syncthreads();
    if (t < 128) {
        float a0 = 0.f, a1 = 0.f;
#pragma unroll 4
        for (int k = 0; k < 256; ++k) {
            float wv = lw3[(size_t)k * 128 + t];
            a0 = fmaf(y2[0][k], wv, a0);
            a1 = fmaf(y2[1][k], wv, a1);
        }
        y3[0][t] = fmaxf(a0 + lb3[t], 0.f);
        y3[1][t] = fmaxf(a1 + lb3[t], 0.f);
    }
    __syncthreads();
    if (t < 64) {
        float a0 = 0.f, a1 = 0.f;
#pragma unroll 4
        for (int k = 0; k < 128; ++k) {
            float wv = lw4[(size_t)k * 64 + t];
            a0 = fmaf(y3[0][k], wv, a0);
            a1 = fmaf(y3[1][k], wv, a1);
        }
        y4[0][t] = fmaxf(a0 + lb4[t], 0.f);
        y4[1][t] = fmaxf(a1 + lb4[t], 0.f);
    }
    __syncthreads();
    const int wv = t >> 6, ln = t & 63;
    if (wv < 2) {
        float v = y4[wv][ln] * lw5[ln];
#pragma unroll
        for (int off = 32; off; off >>= 1) v += __shfl_down(v, off);
        if (ln == 0) out[r0 + wv] = 1.f / (1.f + expf(-(v + lb5[0])));
    }
}

// ---------------------------------------------------------------------------
extern "C" void kernel_launch(void* const* d_in, const int* in_sizes, int n_in,
                              void* d_out, int out_size, void* d_ws, size_t ws_size,
                              hipStream_t stream)
{
    const int*   x_ids = (const int*)d_in[0];
    const int*   esrc  = (const int*)d_in[1];
    const int*   edst  = (const int*)d_in[2];
    const float* emb   = (const float*)d_in[3];
    const float* w1l = (const float*)d_in[4],  *b1l = (const float*)d_in[5],  *w1r = (const float*)d_in[6];
    const float* w2l = (const float*)d_in[7],  *b2l = (const float*)d_in[8],  *w2r = (const float*)d_in[9];
    const float* w3l = (const float*)d_in[10], *b3l = (const float*)d_in[11], *w3r = (const float*)d_in[12];
    const float* p1  = (const float*)d_in[13];
    const float* p2  = (const float*)d_in[14];
    const float* p3  = (const float*)d_in[15];
    const float* lw1 = (const float*)d_in[16], *lb1 = (const float*)d_in[17];
    const float* lw2 = (const float*)d_in[18], *lb2 = (const float*)d_in[19];
    const float* lw3 = (const float*)d_in[20], *lb3 = (const float*)d_in[21];
    const float* lw4 = (const float*)d_in[22], *lb4 = (const float*)d_in[23];
    const float* lw5 = (const float*)d_in[24], *lb5 = (const float*)d_in[25];
    float* out = (float*)d_out;

    // ---- workspace layout ----
    const size_t PL = (size_t)65536 * DIM;
    unsigned short* Xhi = (unsigned short*)d_ws;
    unsigned short* Xlo = Xhi + PL;
    unsigned short* Ghi = Xlo + PL;
    unsigned short* Glo = Ghi + PL;
    float* Cc  = (float*)(Glo + PL);
    float* H   = Cc + PL;
    float* SC4 = H + (size_t)1024 * 1024;            // 65536*4 floats
    uint*  SE1 = (uint*)(SC4 + (size_t)65536 * 4);
    uint*  SE2 = SE1 + ETOT;
    uint*  SE3 = SE2 + ETOT;
    int*   OF1 = (int*)(SE3 + ETOT);
    int*   OF2 = OF1 + BG * OFS;
    int*   OF3 = OF2 + BG * OFS;
    unsigned short* WT = (unsigned short*)(OF3 + BG * OFS);  // 12 planes x 512*512
    const size_t WSZ = (size_t)DIM * DIM;
    unsigned short *w1lh = WT + 0*WSZ,  *w1ll = WT + 1*WSZ;
    unsigned short *w1rh = WT + 2*WSZ,  *w1rl = WT + 3*WSZ;
    unsigned short *w2lh = WT + 4*WSZ,  *w2ll = WT + 5*WSZ;
    unsigned short *w2rh = WT + 6*WSZ,  *w2rl = WT + 7*WSZ;
    unsigned short *w3lh = WT + 8*WSZ,  *w3ll = WT + 9*WSZ;
    unsigned short *w3rh = WT + 10*WSZ, *w3rl = WT + 11*WSZ;

    // ---- weight conversion ----
    WPtrs wp;
    wp.w[0] = w1l; wp.w[1] = w1r; wp.w[2] = w2l;
    wp.w[3] = w2r; wp.w[4] = w3l; wp.w[5] = w3r;
    split_wT_all<<<6 * 256, 256, 0, stream>>>(wp, WT);

    // ---- layer 1 ----
    gather_split<<<16384, 256, 0, stream>>>(x_ids, emb, Xhi, Xlo);
    sort_edges1<<<BG, 256, 0, stream>>>(esrc, edst, SE1, OF1);
    agg_sorted<64><<<BG * 4, 256, 0, stream>>>(Xhi, Xlo, SE1, OF1, Ghi, Glo);
    gemm_sage<<<(65536/128)*4, 256, 0, stream>>>(Ghi, Glo, w1lh, w1ll,
                                                 Xhi, Xlo, w1rh, w1rl,
                                                 b1l, p1, Cc, SC4, 65536);
    pool_fused<64, KP1, true, true><<<BG, 256, 0, stream>>>(
        Cc, p1, SC4, Xhi, Xlo, SE1, OF1, SE2, OF2, H);

    // ---- layer 2 ----
    agg_sorted<KP1><<<BG * 4, 256, 0, stream>>>(Xhi, Xlo, SE2, OF2, Ghi, Glo);
    gemm_sage<<<(53248/128)*4, 256, 0, stream>>>(Ghi, Glo, w2lh, w2ll,
                                                 Xhi, Xlo, w2rh, w2rl,
                                                 b2l, p2, Cc, SC4, 53248);
    pool_fused<KP1, KP2, true, false><<<BG, 256, 0, stream>>>(
        Cc, p2, SC4, Xhi, Xlo, SE2, OF2, SE3, OF3, H);

    // ---- layer 3 ----
    agg_sorted<KP2><<<BG * 4, 256, 0, stream>>>(Xhi, Xlo, SE3, OF3, Ghi, Glo);
    gemm_sage<<<(43008/128)*4, 256, 0, stream>>>(Ghi, Glo, w3lh, w3ll,
                                                 Xhi, Xlo, w3rh, w3rl,
                                                 b3l, p3, Cc, SC4, 43008);
    pool_fused<KP2, KP3, false, false><<<BG, 256, 0, stream>>>(
        Cc, p3, SC4, Xhi, Xlo, nullptr, nullptr, nullptr, nullptr, H);

    // ---- fused MLP head ----
    mlp_fused<<<512, 256, 0, stream>>>(H, lw1, lb1, lw2, lb2, lw3, lb3,
                                       lw4, lb4, lw5, lb5, out);
}